// Round 1
// baseline (3469.811 us; speedup 1.0000x reference)
//
#include <hip/hip_runtime.h>

#define NN 50000
#define NE 800000
#define ET (NE + NN)   // 850000 edges incl. self-loops

// ---- monotone float<->uint encoding for atomicMax on floats ----
__device__ __forceinline__ unsigned encf(float f) {
    unsigned b = __float_as_uint(f);
    return (b & 0x80000000u) ? ~b : (b | 0x80000000u);
}
__device__ __forceinline__ float decf(unsigned u) {
    unsigned b = (u & 0x80000000u) ? (u & 0x7FFFFFFFu) : ~u;
    return __uint_as_float(b);
}
#define ENC_NEG_INF 0x007FFFFFu   // encf(-inf)

__device__ __forceinline__ float lrelu(float a) { return a > 0.f ? a : 0.2f * a; }

// ---- init: amax to -inf, denoms to 0, d_out to b2 ----
__global__ void k_init(unsigned* __restrict__ am1, float* __restrict__ dn1,
                       unsigned* __restrict__ am2, float* __restrict__ dn2,
                       const float* __restrict__ b2, float* __restrict__ out) {
    int i = blockIdx.x * blockDim.x + threadIdx.x;
    if (i < NN * 4) { am1[i] = ENC_NEG_INF; dn1[i] = 0.f; }
    if (i < NN)     { am2[i] = ENC_NEG_INF; dn2[i] = 0.f; }
    if (i < 128)    out[i] = b2[i];
}

// ---- layer1 node transform: h1 = x@W1 ; per-head attention dots ----
__global__ __launch_bounds__(128) void k_node1(
        const float* __restrict__ x, const float* __restrict__ W1,
        const float* __restrict__ attس_unused, // placeholder never used
        const float* __restrict__ as1, const float* __restrict__ ad1,
        float* __restrict__ h, float* __restrict__ asrc, float* __restrict__ adst) {
    int n = blockIdx.x, c = threadIdx.x;
    float x0 = x[2 * n], x1 = x[2 * n + 1];
    float hv = fmaf(x0, W1[c], x1 * W1[128 + c]);
    h[n * 128 + c] = hv;
    float ps = hv * as1[c], pd = hv * ad1[c];
#pragma unroll
    for (int m = 16; m >= 1; m >>= 1) {
        ps += __shfl_xor(ps, m);
        pd += __shfl_xor(pd, m);
    }
    if ((c & 31) == 0) {
        int hd = c >> 5;
        asrc[n * 4 + hd] = ps;
        adst[n * 4 + hd] = pd;
    }
}

// ---- layer1 edge pass A: segment max ----
__global__ void k_emax1(const int* __restrict__ ei, const float* __restrict__ asrc,
                        const float* __restrict__ adst, unsigned* __restrict__ amax) {
    int e = blockIdx.x * blockDim.x + threadIdx.x;
    if (e >= ET) return;
    int s, d;
    if (e < NE) { s = ei[e]; d = ei[NE + e]; } else { s = d = e - NE; }
    float4 a = *(const float4*)(asrc + s * 4);
    float4 b = *(const float4*)(adst + d * 4);
    atomicMax(amax + d * 4 + 0, encf(lrelu(a.x + b.x)));
    atomicMax(amax + d * 4 + 1, encf(lrelu(a.y + b.y)));
    atomicMax(amax + d * 4 + 2, encf(lrelu(a.z + b.z)));
    atomicMax(amax + d * 4 + 3, encf(lrelu(a.w + b.w)));
}

// ---- layer1 edge pass B: exp + segment sum ----
__global__ void k_eden1(const int* __restrict__ ei, const float* __restrict__ asrc,
                        const float* __restrict__ adst, const unsigned* __restrict__ amax,
                        float* __restrict__ den) {
    int e = blockIdx.x * blockDim.x + threadIdx.x;
    if (e >= ET) return;
    int s, d;
    if (e < NE) { s = ei[e]; d = ei[NE + e]; } else { s = d = e - NE; }
    float4 a = *(const float4*)(asrc + s * 4);
    float4 b = *(const float4*)(adst + d * 4);
    uint4 m = *(const uint4*)(amax + d * 4);
    atomicAdd(den + d * 4 + 0, expf(lrelu(a.x + b.x) - decf(m.x)));
    atomicAdd(den + d * 4 + 1, expf(lrelu(a.y + b.y) - decf(m.y)));
    atomicAdd(den + d * 4 + 2, expf(lrelu(a.z + b.z) - decf(m.z)));
    atomicAdd(den + d * 4 + 3, expf(lrelu(a.w + b.w) - decf(m.w)));
}

// ---- layer1 edge pass C: weighted scatter-add of messages (32 lanes/edge) ----
__global__ void k_eagg1(const int* __restrict__ ei, const float* __restrict__ asrc,
                        const float* __restrict__ adst, const unsigned* __restrict__ amax,
                        const float* __restrict__ den, const float* __restrict__ h,
                        float* __restrict__ ob) {
    int g = (blockIdx.x * blockDim.x + threadIdx.x) >> 5;  // edge id
    int l = threadIdx.x & 31;
    if (g >= ET) return;
    int s, d;
    if (g < NE) { s = ei[g]; d = ei[NE + g]; } else { s = d = g - NE; }
    int hd = l >> 3;                 // head for this lane's 4 channels
    float al = lrelu(asrc[s * 4 + hd] + adst[d * 4 + hd]);
    float coef = expf(al - decf(amax[d * 4 + hd])) / (den[d * 4 + hd] + 1e-16f);
    int c0 = l * 4;
    float4 hv = *(const float4*)(h + s * 128 + c0);
    float* op = ob + d * 128 + c0;
    atomicAdd(op + 0, hv.x * coef);
    atomicAdd(op + 1, hv.y * coef);
    atomicAdd(op + 2, hv.z * coef);
    atomicAdd(op + 3, hv.w * coef);
}

// ---- layer2 node transform: x2 = relu(out1+b1); h2 = x2@W2 ; attention dots ----
__global__ __launch_bounds__(128) void k_node2(
        const float* __restrict__ ob, const float* __restrict__ b1,
        const float* __restrict__ W2, const float* __restrict__ as2,
        const float* __restrict__ ad2, float* __restrict__ h2,
        float* __restrict__ asrc, float* __restrict__ adst) {
    __shared__ float Wl[128 * 128];
    __shared__ float xrow[128];
    __shared__ float rs[2], rd[2];
    int c = threadIdx.x;
    for (int i = c; i < 128 * 128; i += 128) Wl[i] = W2[i];
    __syncthreads();
    for (int n = blockIdx.x; n < NN; n += gridDim.x) {
        float xv = fmaxf(ob[n * 128 + c] + b1[c], 0.f);
        xrow[c] = xv;
        __syncthreads();
        float acc0 = 0.f, acc1 = 0.f;
#pragma unroll
        for (int k = 0; k < 128; k += 2) {
            acc0 = fmaf(xrow[k], Wl[k * 128 + c], acc0);
            acc1 = fmaf(xrow[k + 1], Wl[(k + 1) * 128 + c], acc1);
        }
        float acc = acc0 + acc1;
        h2[n * 128 + c] = acc;
        float ps = acc * as2[c], pd = acc * ad2[c];
#pragma unroll
        for (int m = 32; m >= 1; m >>= 1) {
            ps += __shfl_xor(ps, m);
            pd += __shfl_xor(pd, m);
        }
        if ((c & 63) == 0) { rs[c >> 6] = ps; rd[c >> 6] = pd; }
        __syncthreads();
        if (c == 0) { asrc[n] = rs[0] + rs[1]; adst[n] = rd[0] + rd[1]; }
        // next iteration's xrow write is safe: all reads happened before the
        // barrier above; rs/rd rewritten only after the next barrier.
    }
}

// ---- layer2 edge passes (heads = 1) ----
__global__ void k_emax2(const int* __restrict__ ei, const float* __restrict__ asrc,
                        const float* __restrict__ adst, unsigned* __restrict__ amax) {
    int e = blockIdx.x * blockDim.x + threadIdx.x;
    if (e >= ET) return;
    int s, d;
    if (e < NE) { s = ei[e]; d = ei[NE + e]; } else { s = d = e - NE; }
    atomicMax(amax + d, encf(lrelu(asrc[s] + adst[d])));
}

__global__ void k_eden2(const int* __restrict__ ei, const float* __restrict__ asrc,
                        const float* __restrict__ adst, const unsigned* __restrict__ amax,
                        float* __restrict__ den) {
    int e = blockIdx.x * blockDim.x + threadIdx.x;
    if (e >= ET) return;
    int s, d;
    if (e < NE) { s = ei[e]; d = ei[NE + e]; } else { s = d = e - NE; }
    float al = lrelu(asrc[s] + adst[d]);
    atomicAdd(den + d, expf(al - decf(amax[d])));
}

__global__ void k_eagg2(const int* __restrict__ ei, const float* __restrict__ asrc,
                        const float* __restrict__ adst, const unsigned* __restrict__ amax,
                        const float* __restrict__ den, const float* __restrict__ h,
                        float* __restrict__ ob) {
    int g = (blockIdx.x * blockDim.x + threadIdx.x) >> 5;
    int l = threadIdx.x & 31;
    if (g >= ET) return;
    int s, d;
    if (g < NE) { s = ei[g]; d = ei[NE + g]; } else { s = d = g - NE; }
    float al = lrelu(asrc[s] + adst[d]);
    float coef = expf(al - decf(amax[d])) / (den[d] + 1e-16f);
    int c0 = l * 4;
    float4 hv = *(const float4*)(h + s * 128 + c0);
    float* op = ob + d * 128 + c0;
    atomicAdd(op + 0, hv.x * coef);
    atomicAdd(op + 1, hv.y * coef);
    atomicAdd(op + 2, hv.z * coef);
    atomicAdd(op + 3, hv.w * coef);
}

// ---- final: mean over nodes, d_out pre-set to b2 ----
__global__ __launch_bounds__(128) void k_final(const float* __restrict__ ob,
                                               float* __restrict__ out) {
    int c = threadIdx.x;
    float acc = 0.f;
    for (int n = blockIdx.x; n < NN; n += gridDim.x) acc += ob[n * 128 + c];
    atomicAdd(out + c, acc * (1.0f / NN));
}

extern "C" void kernel_launch(void* const* d_in, const int* in_sizes, int n_in,
                              void* d_out, int out_size, void* d_ws, size_t ws_size,
                              hipStream_t stream) {
    const float* x   = (const float*)d_in[0];
    const int*   ei  = (const int*)d_in[1];
    const float* W1  = (const float*)d_in[2];
    const float* as1 = (const float*)d_in[3];
    const float* ad1 = (const float*)d_in[4];
    const float* b1  = (const float*)d_in[5];
    const float* W2  = (const float*)d_in[6];
    const float* as2 = (const float*)d_in[7];
    const float* ad2 = (const float*)d_in[8];
    const float* b2  = (const float*)d_in[9];
    float* out = (float*)d_out;

    float* ws   = (float*)d_ws;
    float* h    = ws;                 // N*128, h1 then h2
    float* ob   = h + NN * 128;       // N*128, out1 then out2
    float* asr1 = ob + NN * 128;      // N*4
    float* adt1 = asr1 + NN * 4;      // N*4
    unsigned* am1 = (unsigned*)(adt1 + NN * 4);   // N*4
    float* dn1  = (float*)(am1 + NN * 4);         // N*4
    float* asr2 = dn1 + NN * 4;       // N
    float* adt2 = asr2 + NN;          // N
    unsigned* am2 = (unsigned*)(adt2 + NN);       // N
    float* dn2  = (float*)(am2 + NN);             // N

    hipMemsetAsync(ob, 0, (size_t)NN * 128 * 4, stream);
    k_init<<<(NN * 4 + 255) / 256, 256, 0, stream>>>(am1, dn1, am2, dn2, b2, out);

    // layer 1
    k_node1<<<NN, 128, 0, stream>>>(x, W1, nullptr, as1, ad1, h, asr1, adt1);
    k_emax1<<<(ET + 255) / 256, 256, 0, stream>>>(ei, asr1, adt1, am1);
    k_eden1<<<(ET + 255) / 256, 256, 0, stream>>>(ei, asr1, adt1, am1, dn1);
    k_eagg1<<<((size_t)ET * 32 + 255) / 256, 256, 0, stream>>>(ei, asr1, adt1, am1, dn1, h, ob);

    // layer 2 node transform (consumes out1, overwrites h with h2)
    k_node2<<<512, 128, 0, stream>>>(ob, b1, W2, as2, ad2, h, asr2, adt2);
    hipMemsetAsync(ob, 0, (size_t)NN * 128 * 4, stream);

    // layer 2 edges
    k_emax2<<<(ET + 255) / 256, 256, 0, stream>>>(ei, asr2, adt2, am2);
    k_eden2<<<(ET + 255) / 256, 256, 0, stream>>>(ei, asr2, adt2, am2, dn2);
    k_eagg2<<<((size_t)ET * 32 + 255) / 256, 256, 0, stream>>>(ei, asr2, adt2, am2, dn2, h, ob);

    // mean pool (+b2 already in out)
    k_final<<<256, 128, 0, stream>>>(ob, out);
}

// Round 2
// 603.574 us; speedup vs baseline: 5.7488x; 5.7488x over previous
//
#include <hip/hip_runtime.h>

#define NN 50000
#define NE 800000
#define ET (NE + NN)   // 850000 edges incl. self-loops
#define SCAN_B 256
#define NBLK ((NN + SCAN_B - 1) / SCAN_B)   // 196

__device__ __forceinline__ float lrelu(float a) { return a > 0.f ? a : 0.2f * a; }

// ---- init: zero degrees, d_out = b2 ----
__global__ void k_init(int* __restrict__ deg, const float* __restrict__ b2,
                       float* __restrict__ out) {
    int i = blockIdx.x * blockDim.x + threadIdx.x;
    if (i < NN)  deg[i] = 0;
    if (i < 128) out[i] = b2[i];
}

// ---- CSR build: degree count ----
__global__ void k_deg(const int* __restrict__ ei, int* __restrict__ deg) {
    int e = blockIdx.x * blockDim.x + threadIdx.x;
    if (e >= ET) return;
    int d = (e < NE) ? ei[NE + e] : e - NE;
    atomicAdd(deg + d, 1);
}

// ---- scan stage A: per-block exclusive scan + block sums ----
__global__ __launch_bounds__(SCAN_B) void k_scan_a(const int* __restrict__ deg,
                                                   int* __restrict__ off,
                                                   int* __restrict__ bsum) {
    __shared__ int sh[SCAN_B];
    int t = threadIdx.x, i = blockIdx.x * SCAN_B + t;
    int v = (i < NN) ? deg[i] : 0;
    sh[t] = v;
    __syncthreads();
#pragma unroll
    for (int s = 1; s < SCAN_B; s <<= 1) {
        int u = (t >= s) ? sh[t - s] : 0;
        __syncthreads();
        sh[t] += u;
        __syncthreads();
    }
    if (i < NN) off[i] = sh[t] - v;          // local exclusive
    if (t == SCAN_B - 1) bsum[blockIdx.x] = sh[t];
}

// ---- scan stage B: exclusive scan of block sums (single block) ----
__global__ __launch_bounds__(SCAN_B) void k_scan_b(int* __restrict__ bsum,
                                                   int* __restrict__ off) {
    __shared__ int sh[SCAN_B];
    int t = threadIdx.x;
    int v = (t < NBLK) ? bsum[t] : 0;
    sh[t] = v;
    __syncthreads();
#pragma unroll
    for (int s = 1; s < SCAN_B; s <<= 1) {
        int u = (t >= s) ? sh[t - s] : 0;
        __syncthreads();
        sh[t] += u;
        __syncthreads();
    }
    if (t < NBLK) bsum[t] = sh[t] - v;       // exclusive bases
    if (t == 0) off[NN] = ET;
}

// ---- scan stage C: add bases; copy to cursor ----
__global__ __launch_bounds__(SCAN_B) void k_scan_c(int* __restrict__ off,
                                                   const int* __restrict__ bsum,
                                                   int* __restrict__ cur) {
    int i = blockIdx.x * SCAN_B + threadIdx.x;
    if (i >= NN) return;
    int o = off[i] + bsum[blockIdx.x];
    off[i] = o;
    cur[i] = o;
}

// ---- CSR fill: csr_src[slot] = src ----
__global__ void k_fill(const int* __restrict__ ei, int* __restrict__ cur,
                       int* __restrict__ csr) {
    int e = blockIdx.x * blockDim.x + threadIdx.x;
    if (e >= ET) return;
    int s, d;
    if (e < NE) { s = ei[e]; d = ei[NE + e]; } else { s = d = e - NE; }
    int pos = atomicAdd(cur + d, 1);
    csr[pos] = s;
}

// ---- layer1 node transform: h1 = x@W1 ; per-head attention dots ----
__global__ __launch_bounds__(128) void k_node1(
        const float* __restrict__ x, const float* __restrict__ W1,
        const float* __restrict__ as1, const float* __restrict__ ad1,
        float* __restrict__ h, float* __restrict__ asrc, float* __restrict__ adst) {
    int n = blockIdx.x, c = threadIdx.x;
    float x0 = x[2 * n], x1 = x[2 * n + 1];
    float hv = fmaf(x0, W1[c], x1 * W1[128 + c]);
    h[n * 128 + c] = hv;
    float ps = hv * as1[c], pd = hv * ad1[c];
#pragma unroll
    for (int m = 16; m >= 1; m >>= 1) {
        ps += __shfl_xor(ps, m);
        pd += __shfl_xor(pd, m);
    }
    if ((c & 31) == 0) {
        int hd = c >> 5;
        asrc[n * 4 + hd] = ps;
        adst[n * 4 + hd] = pd;
    }
}

// ---- layer1 gather-aggregate: one block (128 thr) per dst node, heads=4 ----
__global__ __launch_bounds__(128) void k_agg1(
        const int* __restrict__ off, const int* __restrict__ csr,
        const float* __restrict__ asrc, const float* __restrict__ adst,
        const float* __restrict__ h, float* __restrict__ ob) {
    int n = blockIdx.x, c = threadIdx.x, hd = c >> 5;
    int e0 = off[n], e1 = off[n + 1];
    float ad = adst[n * 4 + hd];
    float amax = -1e30f;
    for (int e = e0; e < e1; ++e) {
        int s = csr[e];
        amax = fmaxf(amax, lrelu(asrc[s * 4 + hd] + ad));
    }
    float den = 0.f, acc = 0.f;
    for (int e = e0; e < e1; ++e) {
        int s = csr[e];
        float ex = __expf(lrelu(asrc[s * 4 + hd] + ad) - amax);
        den += ex;
        acc = fmaf(ex, h[s * 128 + c], acc);
    }
    ob[n * 128 + c] = acc / (den + 1e-16f);
}

// ---- layer2 node transform: x2 = relu(out1+b1); h2 = x2@W2 ; attn dots ----
__global__ __launch_bounds__(128) void k_node2(
        const float* __restrict__ ob, const float* __restrict__ b1,
        const float* __restrict__ W2, const float* __restrict__ as2,
        const float* __restrict__ ad2, float* __restrict__ h2,
        float* __restrict__ asrc, float* __restrict__ adst) {
    __shared__ float Wl[128 * 128];
    __shared__ float xrow[128];
    __shared__ float rs[2], rd[2];
    int c = threadIdx.x;
    for (int i = c; i < 128 * 128; i += 128) Wl[i] = W2[i];
    __syncthreads();
    for (int n = blockIdx.x; n < NN; n += gridDim.x) {
        float xv = fmaxf(ob[n * 128 + c] + b1[c], 0.f);
        xrow[c] = xv;
        __syncthreads();
        float acc0 = 0.f, acc1 = 0.f;
#pragma unroll
        for (int k = 0; k < 128; k += 2) {
            acc0 = fmaf(xrow[k], Wl[k * 128 + c], acc0);
            acc1 = fmaf(xrow[k + 1], Wl[(k + 1) * 128 + c], acc1);
        }
        float acc = acc0 + acc1;
        h2[n * 128 + c] = acc;
        float ps = acc * as2[c], pd = acc * ad2[c];
#pragma unroll
        for (int m = 32; m >= 1; m >>= 1) {
            ps += __shfl_xor(ps, m);
            pd += __shfl_xor(pd, m);
        }
        if ((c & 63) == 0) { rs[c >> 6] = ps; rd[c >> 6] = pd; }
        __syncthreads();
        if (c == 0) { asrc[n] = rs[0] + rs[1]; adst[n] = rd[0] + rd[1]; }
    }
}

// ---- layer2 gather-aggregate: heads=1 ----
__global__ __launch_bounds__(128) void k_agg2(
        const int* __restrict__ off, const int* __restrict__ csr,
        const float* __restrict__ asrc, const float* __restrict__ adst,
        const float* __restrict__ h, float* __restrict__ ob) {
    int n = blockIdx.x, c = threadIdx.x;
    int e0 = off[n], e1 = off[n + 1];
    float ad = adst[n];
    float amax = -1e30f;
    for (int e = e0; e < e1; ++e) {
        int s = csr[e];
        amax = fmaxf(amax, lrelu(asrc[s] + ad));
    }
    float den = 0.f, acc = 0.f;
    for (int e = e0; e < e1; ++e) {
        int s = csr[e];
        float ex = __expf(lrelu(asrc[s] + ad) - amax);
        den += ex;
        acc = fmaf(ex, h[s * 128 + c], acc);
    }
    ob[n * 128 + c] = acc / (den + 1e-16f);
}

// ---- final: mean over nodes, d_out pre-set to b2 ----
__global__ __launch_bounds__(128) void k_final(const float* __restrict__ ob,
                                               float* __restrict__ out) {
    int c = threadIdx.x;
    float acc = 0.f;
    for (int n = blockIdx.x; n < NN; n += gridDim.x) acc += ob[n * 128 + c];
    atomicAdd(out + c, acc * (1.0f / NN));
}

extern "C" void kernel_launch(void* const* d_in, const int* in_sizes, int n_in,
                              void* d_out, int out_size, void* d_ws, size_t ws_size,
                              hipStream_t stream) {
    const float* x   = (const float*)d_in[0];
    const int*   ei  = (const int*)d_in[1];
    const float* W1  = (const float*)d_in[2];
    const float* as1 = (const float*)d_in[3];
    const float* ad1 = (const float*)d_in[4];
    const float* b1  = (const float*)d_in[5];
    const float* W2  = (const float*)d_in[6];
    const float* as2 = (const float*)d_in[7];
    const float* ad2 = (const float*)d_in[8];
    const float* b2  = (const float*)d_in[9];
    float* out = (float*)d_out;

    float* ws   = (float*)d_ws;
    float* h    = ws;                    // NN*128 (h1 then h2)
    float* ob   = h + NN * 128;          // NN*128 (out1 then out2)
    float* asr1 = ob + NN * 128;         // NN*4
    float* adt1 = asr1 + NN * 4;         // NN*4
    float* asr2 = adt1 + NN * 4;         // NN
    float* adt2 = asr2 + NN;             // NN
    int* deg    = (int*)(adt2 + NN);     // NN
    int* off    = deg + NN;              // NN+1
    int* cur    = off + NN + 1;          // NN
    int* bsum   = cur + NN;              // NBLK
    int* csr    = bsum + NBLK;           // ET

    // CSR build (shared by both layers)
    k_init<<<(NN + 255) / 256, 256, 0, stream>>>(deg, b2, out);
    k_deg<<<(ET + 255) / 256, 256, 0, stream>>>(ei, deg);
    k_scan_a<<<NBLK, SCAN_B, 0, stream>>>(deg, off, bsum);
    k_scan_b<<<1, SCAN_B, 0, stream>>>(bsum, off);
    k_scan_c<<<NBLK, SCAN_B, 0, stream>>>(off, bsum, cur);
    k_fill<<<(ET + 255) / 256, 256, 0, stream>>>(ei, cur, csr);

    // layer 1
    k_node1<<<NN, 128, 0, stream>>>(x, W1, as1, ad1, h, asr1, adt1);
    k_agg1<<<NN, 128, 0, stream>>>(off, csr, asr1, adt1, h, ob);

    // layer 2 (h reused for h2, ob overwritten by out2)
    k_node2<<<512, 128, 0, stream>>>(ob, b1, W2, as2, ad2, h, asr2, adt2);
    k_agg2<<<NN, 128, 0, stream>>>(off, csr, asr2, adt2, h, ob);

    // mean pool (+b2 already in out)
    k_final<<<256, 128, 0, stream>>>(ob, out);
}

// Round 3
// 395.915 us; speedup vs baseline: 8.7640x; 1.5245x over previous
//
#include <hip/hip_runtime.h>

#define NN 50000
#define NE 800000
#define ET (NE + NN)   // 850000 edges incl. self-loops
#define SCAN_B 256
#define NBLK ((NN + SCAN_B - 1) / SCAN_B)   // 196

__device__ __forceinline__ float lrelu(float a) { return a > 0.f ? a : 0.2f * a; }

// ---- init: zero degrees, d_out = b2 ----
__global__ void k_init(int* __restrict__ deg, const float* __restrict__ b2,
                       float* __restrict__ out) {
    int i = blockIdx.x * blockDim.x + threadIdx.x;
    if (i < NN)  deg[i] = 0;
    if (i < 128) out[i] = b2[i];
}

// ---- CSR build: degree count ----
__global__ void k_deg(const int* __restrict__ ei, int* __restrict__ deg) {
    int e = blockIdx.x * blockDim.x + threadIdx.x;
    if (e >= ET) return;
    int d = (e < NE) ? ei[NE + e] : e - NE;
    atomicAdd(deg + d, 1);
}

// ---- scan stage A: per-block exclusive scan + block sums ----
__global__ __launch_bounds__(SCAN_B) void k_scan_a(const int* __restrict__ deg,
                                                   int* __restrict__ off,
                                                   int* __restrict__ bsum) {
    __shared__ int sh[SCAN_B];
    int t = threadIdx.x, i = blockIdx.x * SCAN_B + t;
    int v = (i < NN) ? deg[i] : 0;
    sh[t] = v;
    __syncthreads();
#pragma unroll
    for (int s = 1; s < SCAN_B; s <<= 1) {
        int u = (t >= s) ? sh[t - s] : 0;
        __syncthreads();
        sh[t] += u;
        __syncthreads();
    }
    if (i < NN) off[i] = sh[t] - v;          // local exclusive
    if (t == SCAN_B - 1) bsum[blockIdx.x] = sh[t];
}

// ---- scan stage B: exclusive scan of block sums (single block) ----
__global__ __launch_bounds__(SCAN_B) void k_scan_b(int* __restrict__ bsum,
                                                   int* __restrict__ off) {
    __shared__ int sh[SCAN_B];
    int t = threadIdx.x;
    int v = (t < NBLK) ? bsum[t] : 0;
    sh[t] = v;
    __syncthreads();
#pragma unroll
    for (int s = 1; s < SCAN_B; s <<= 1) {
        int u = (t >= s) ? sh[t - s] : 0;
        __syncthreads();
        sh[t] += u;
        __syncthreads();
    }
    if (t < NBLK) bsum[t] = sh[t] - v;       // exclusive bases
    if (t == 0) off[NN] = ET;
}

// ---- scan stage C: add bases; copy to cursor ----
__global__ __launch_bounds__(SCAN_B) void k_scan_c(int* __restrict__ off,
                                                   const int* __restrict__ bsum,
                                                   int* __restrict__ cur) {
    int i = blockIdx.x * SCAN_B + threadIdx.x;
    if (i >= NN) return;
    int o = off[i] + bsum[blockIdx.x];
    off[i] = o;
    cur[i] = o;
}

// ---- CSR fill: csr_src[slot] = src ----
__global__ void k_fill(const int* __restrict__ ei, int* __restrict__ cur,
                       int* __restrict__ csr) {
    int e = blockIdx.x * blockDim.x + threadIdx.x;
    if (e >= ET) return;
    int s, d;
    if (e < NE) { s = ei[e]; d = ei[NE + e]; } else { s = d = e - NE; }
    int pos = atomicAdd(cur + d, 1);
    csr[pos] = s;
}

// ---- layer1 node transform: h1 = x@W1 ; per-head attention dots ----
__global__ __launch_bounds__(128) void k_node1(
        const float* __restrict__ x, const float* __restrict__ W1,
        const float* __restrict__ as1, const float* __restrict__ ad1,
        float* __restrict__ h, float* __restrict__ asrc, float* __restrict__ adst) {
    int n = blockIdx.x, c = threadIdx.x;
    float x0 = x[2 * n], x1 = x[2 * n + 1];
    float hv = fmaf(x0, W1[c], x1 * W1[128 + c]);
    h[n * 128 + c] = hv;
    float ps = hv * as1[c], pd = hv * ad1[c];
#pragma unroll
    for (int m = 16; m >= 1; m >>= 1) {
        ps += __shfl_xor(ps, m);
        pd += __shfl_xor(pd, m);
    }
    if ((c & 31) == 0) {
        int hd = c >> 5;
        asrc[n * 4 + hd] = ps;
        adst[n * 4 + hd] = pd;
    }
}

// ---- layer1 gather-aggregate: one block (128 thr) per dst node, heads=4 ----
__global__ __launch_bounds__(128) void k_agg1(
        const int* __restrict__ off, const int* __restrict__ csr,
        const float* __restrict__ asrc, const float* __restrict__ adst,
        const float* __restrict__ h, float* __restrict__ ob) {
    int n = blockIdx.x, c = threadIdx.x, hd = c >> 5;
    int e0 = off[n], e1 = off[n + 1];
    float ad = adst[n * 4 + hd];
    float amax = -1e30f;
#pragma unroll 4
    for (int e = e0; e < e1; ++e) {
        int s = csr[e];
        amax = fmaxf(amax, lrelu(asrc[s * 4 + hd] + ad));
    }
    float den = 0.f, acc = 0.f;
#pragma unroll 4
    for (int e = e0; e < e1; ++e) {
        int s = csr[e];
        float ex = __expf(lrelu(asrc[s * 4 + hd] + ad) - amax);
        den += ex;
        acc = fmaf(ex, h[s * 128 + c], acc);
    }
    ob[n * 128 + c] = acc / (den + 1e-16f);
}

// ---- layer2 node transform, register-tiled GEMM:
//      x2 = relu(out1+b1); h2 = x2@W2 ; fused attention dots
//      block = 256 thr, tile = 32 rows x 128 cols, thread = 4x4 outputs ----
__global__ __launch_bounds__(256) void k_node2t(
        const float* __restrict__ ob, const float* __restrict__ b1,
        const float* __restrict__ W2, const float* __restrict__ as2,
        const float* __restrict__ ad2, float* __restrict__ h2,
        float* __restrict__ asrc, float* __restrict__ adst) {
    __shared__ float Wl[32][128];   // one 32-row K-chunk of W2
    __shared__ float xt[32][128];   // 32 rows of relu(out1+b1)
    int t = threadIdx.x;
    int tc = t & 31, tr = t >> 5;         // col group 0..31, row group 0..7
    int n0 = blockIdx.x * 32;

    // stage x tile (fused bias + relu), 4 float4 per thread
#pragma unroll
    for (int i = 0; i < 4; ++i) {
        int f4 = t + i * 256;             // 0..1023
        int r = f4 >> 5, c4 = f4 & 31;
        float4 v = make_float4(0.f, 0.f, 0.f, 0.f);
        int n = n0 + r;
        if (n < NN) {
            v = *(const float4*)(ob + (size_t)n * 128 + c4 * 4);
            float4 bb = *(const float4*)(b1 + c4 * 4);
            v.x = fmaxf(v.x + bb.x, 0.f);
            v.y = fmaxf(v.y + bb.y, 0.f);
            v.z = fmaxf(v.z + bb.z, 0.f);
            v.w = fmaxf(v.w + bb.w, 0.f);
        }
        *(float4*)(&xt[r][c4 * 4]) = v;
    }

    float acc[4][4] = {{0.f}};
#pragma unroll
    for (int kc = 0; kc < 4; ++kc) {
        __syncthreads();                  // xt ready / prev W chunk consumed
#pragma unroll
        for (int i = 0; i < 4; ++i) {
            int f4 = t + i * 256;
            int r = f4 >> 5, c4 = f4 & 31;
            *(float4*)(&Wl[r][c4 * 4]) =
                *(const float4*)(W2 + (size_t)(kc * 32 + r) * 128 + c4 * 4);
        }
        __syncthreads();
#pragma unroll
        for (int k = 0; k < 32; ++k) {
            float4 w = *(const float4*)(&Wl[k][tc * 4]);
            float x0 = xt[tr * 4 + 0][kc * 32 + k];
            float x1 = xt[tr * 4 + 1][kc * 32 + k];
            float x2 = xt[tr * 4 + 2][kc * 32 + k];
            float x3 = xt[tr * 4 + 3][kc * 32 + k];
            acc[0][0] = fmaf(x0, w.x, acc[0][0]);
            acc[0][1] = fmaf(x0, w.y, acc[0][1]);
            acc[0][2] = fmaf(x0, w.z, acc[0][2]);
            acc[0][3] = fmaf(x0, w.w, acc[0][3]);
            acc[1][0] = fmaf(x1, w.x, acc[1][0]);
            acc[1][1] = fmaf(x1, w.y, acc[1][1]);
            acc[1][2] = fmaf(x1, w.z, acc[1][2]);
            acc[1][3] = fmaf(x1, w.w, acc[1][3]);
            acc[2][0] = fmaf(x2, w.x, acc[2][0]);
            acc[2][1] = fmaf(x2, w.y, acc[2][1]);
            acc[2][2] = fmaf(x2, w.z, acc[2][2]);
            acc[2][3] = fmaf(x2, w.w, acc[2][3]);
            acc[3][0] = fmaf(x3, w.x, acc[3][0]);
            acc[3][1] = fmaf(x3, w.y, acc[3][1]);
            acc[3][2] = fmaf(x3, w.z, acc[3][2]);
            acc[3][3] = fmaf(x3, w.w, acc[3][3]);
        }
    }

    // epilogue: store h2, fused attention dots (reduce over 32 tc lanes)
    float4 av = *(const float4*)(as2 + tc * 4);
    float4 dv = *(const float4*)(ad2 + tc * 4);
#pragma unroll
    for (int j = 0; j < 4; ++j) {
        int n = n0 + tr * 4 + j;
        float ps = acc[j][0] * av.x + acc[j][1] * av.y +
                   acc[j][2] * av.z + acc[j][3] * av.w;
        float pd = acc[j][0] * dv.x + acc[j][1] * dv.y +
                   acc[j][2] * dv.z + acc[j][3] * dv.w;
#pragma unroll
        for (int m = 16; m >= 1; m >>= 1) {
            ps += __shfl_xor(ps, m);
            pd += __shfl_xor(pd, m);
        }
        if (n < NN) {
            *(float4*)(h2 + (size_t)n * 128 + tc * 4) =
                make_float4(acc[j][0], acc[j][1], acc[j][2], acc[j][3]);
            if (tc == 0) { asrc[n] = ps; adst[n] = pd; }
        }
    }
}

// ---- layer2 gather-aggregate: heads=1 ----
__global__ __launch_bounds__(128) void k_agg2(
        const int* __restrict__ off, const int* __restrict__ csr,
        const float* __restrict__ asrc, const float* __restrict__ adst,
        const float* __restrict__ h, float* __restrict__ ob) {
    int n = blockIdx.x, c = threadIdx.x;
    int e0 = off[n], e1 = off[n + 1];
    float ad = adst[n];
    float amax = -1e30f;
#pragma unroll 4
    for (int e = e0; e < e1; ++e) {
        int s = csr[e];
        amax = fmaxf(amax, lrelu(asrc[s] + ad));
    }
    float den = 0.f, acc = 0.f;
#pragma unroll 4
    for (int e = e0; e < e1; ++e) {
        int s = csr[e];
        float ex = __expf(lrelu(asrc[s] + ad) - amax);
        den += ex;
        acc = fmaf(ex, h[s * 128 + c], acc);
    }
    ob[n * 128 + c] = acc / (den + 1e-16f);
}

// ---- final: mean over nodes, d_out pre-set to b2 ----
__global__ __launch_bounds__(128) void k_final(const float* __restrict__ ob,
                                               float* __restrict__ out) {
    int c = threadIdx.x;
    float acc = 0.f;
    for (int n = blockIdx.x; n < NN; n += gridDim.x) acc += ob[n * 128 + c];
    atomicAdd(out + c, acc * (1.0f / NN));
}

extern "C" void kernel_launch(void* const* d_in, const int* in_sizes, int n_in,
                              void* d_out, int out_size, void* d_ws, size_t ws_size,
                              hipStream_t stream) {
    const float* x   = (const float*)d_in[0];
    const int*   ei  = (const int*)d_in[1];
    const float* W1  = (const float*)d_in[2];
    const float* as1 = (const float*)d_in[3];
    const float* ad1 = (const float*)d_in[4];
    const float* b1  = (const float*)d_in[5];
    const float* W2  = (const float*)d_in[6];
    const float* as2 = (const float*)d_in[7];
    const float* ad2 = (const float*)d_in[8];
    const float* b2  = (const float*)d_in[9];
    float* out = (float*)d_out;

    float* ws   = (float*)d_ws;
    float* h    = ws;                    // NN*128 (h1 then h2)
    float* ob   = h + NN * 128;          // NN*128 (out1 then out2)
    float* asr1 = ob + NN * 128;         // NN*4
    float* adt1 = asr1 + NN * 4;         // NN*4
    float* asr2 = adt1 + NN * 4;         // NN
    float* adt2 = asr2 + NN;             // NN
    int* deg    = (int*)(adt2 + NN);     // NN
    int* off    = deg + NN;              // NN+1
    int* cur    = off + NN + 1;          // NN
    int* bsum   = cur + NN;              // NBLK
    int* csr    = bsum + NBLK;           // ET

    // CSR build (shared by both layers)
    k_init<<<(NN + 255) / 256, 256, 0, stream>>>(deg, b2, out);
    k_deg<<<(ET + 255) / 256, 256, 0, stream>>>(ei, deg);
    k_scan_a<<<NBLK, SCAN_B, 0, stream>>>(deg, off, bsum);
    k_scan_b<<<1, SCAN_B, 0, stream>>>(bsum, off);
    k_scan_c<<<NBLK, SCAN_B, 0, stream>>>(off, bsum, cur);
    k_fill<<<(ET + 255) / 256, 256, 0, stream>>>(ei, cur, csr);

    // layer 1
    k_node1<<<NN, 128, 0, stream>>>(x, W1, as1, ad1, h, asr1, adt1);
    k_agg1<<<NN, 128, 0, stream>>>(off, csr, asr1, adt1, h, ob);

    // layer 2 (h reused for h2, ob overwritten by out2)
    k_node2t<<<(NN + 31) / 32, 256, 0, stream>>>(ob, b1, W2, as2, ad2, h, asr2, adt2);
    k_agg2<<<NN, 128, 0, stream>>>(off, csr, asr2, adt2, h, ob);

    // mean pool (+b2 already in out)
    k_final<<<256, 128, 0, stream>>>(ob, out);
}

// Round 4
// 366.752 us; speedup vs baseline: 9.4609x; 1.0795x over previous
//
#include <hip/hip_runtime.h>

#define NN 50000
#define NE 800000
#define ET (NE + NN)   // 850000 edges incl. self-loops
#define SCAN_B 256
#define NBLK ((NN + SCAN_B - 1) / SCAN_B)   // 196
#define DCAP1 256      // max degree on fast path, layer1 (Poisson(16): max ~45)
#define DCAP2 512      // max degree on fast path, layer2

__device__ __forceinline__ float lrelu(float a) { return a > 0.f ? a : 0.2f * a; }

// ---- init: zero degrees, d_out = b2 ----
__global__ void k_init(int* __restrict__ deg, const float* __restrict__ b2,
                       float* __restrict__ out) {
    int i = blockIdx.x * blockDim.x + threadIdx.x;
    if (i < NN)  deg[i] = 0;
    if (i < 128) out[i] = b2[i];
}

// ---- CSR build: degree count ----
__global__ void k_deg(const int* __restrict__ ei, int* __restrict__ deg) {
    int e = blockIdx.x * blockDim.x + threadIdx.x;
    if (e >= ET) return;
    int d = (e < NE) ? ei[NE + e] : e - NE;
    atomicAdd(deg + d, 1);
}

// ---- scan stage A: per-block exclusive scan + block sums ----
__global__ __launch_bounds__(SCAN_B) void k_scan_a(const int* __restrict__ deg,
                                                   int* __restrict__ off,
                                                   int* __restrict__ bsum) {
    __shared__ int sh[SCAN_B];
    int t = threadIdx.x, i = blockIdx.x * SCAN_B + t;
    int v = (i < NN) ? deg[i] : 0;
    sh[t] = v;
    __syncthreads();
#pragma unroll
    for (int s = 1; s < SCAN_B; s <<= 1) {
        int u = (t >= s) ? sh[t - s] : 0;
        __syncthreads();
        sh[t] += u;
        __syncthreads();
    }
    if (i < NN) off[i] = sh[t] - v;          // local exclusive
    if (t == SCAN_B - 1) bsum[blockIdx.x] = sh[t];
}

// ---- scan stage B: exclusive scan of block sums (single block) ----
__global__ __launch_bounds__(SCAN_B) void k_scan_b(int* __restrict__ bsum,
                                                   int* __restrict__ off) {
    __shared__ int sh[SCAN_B];
    int t = threadIdx.x;
    int v = (t < NBLK) ? bsum[t] : 0;
    sh[t] = v;
    __syncthreads();
#pragma unroll
    for (int s = 1; s < SCAN_B; s <<= 1) {
        int u = (t >= s) ? sh[t - s] : 0;
        __syncthreads();
        sh[t] += u;
        __syncthreads();
    }
    if (t < NBLK) bsum[t] = sh[t] - v;       // exclusive bases
    if (t == 0) off[NN] = ET;
}

// ---- scan stage C: add bases; copy to cursor ----
__global__ __launch_bounds__(SCAN_B) void k_scan_c(int* __restrict__ off,
                                                   const int* __restrict__ bsum,
                                                   int* __restrict__ cur) {
    int i = blockIdx.x * SCAN_B + threadIdx.x;
    if (i >= NN) return;
    int o = off[i] + bsum[blockIdx.x];
    off[i] = o;
    cur[i] = o;
}

// ---- CSR fill: csr_src[slot] = src ----
__global__ void k_fill(const int* __restrict__ ei, int* __restrict__ cur,
                       int* __restrict__ csr) {
    int e = blockIdx.x * blockDim.x + threadIdx.x;
    if (e >= ET) return;
    int s, d;
    if (e < NE) { s = ei[e]; d = ei[NE + e]; } else { s = d = e - NE; }
    int pos = atomicAdd(cur + d, 1);
    csr[pos] = s;
}

// ---- layer1 node transform: h1 = x@W1 ; per-head attention dots ----
__global__ __launch_bounds__(128) void k_node1(
        const float* __restrict__ x, const float* __restrict__ W1,
        const float* __restrict__ as1, const float* __restrict__ ad1,
        float* __restrict__ h, float* __restrict__ asrc, float* __restrict__ adst) {
    int n = blockIdx.x, c = threadIdx.x;
    float x0 = x[2 * n], x1 = x[2 * n + 1];
    float hv = fmaf(x0, W1[c], x1 * W1[128 + c]);
    h[n * 128 + c] = hv;
    float ps = hv * as1[c], pd = hv * ad1[c];
#pragma unroll
    for (int m = 16; m >= 1; m >>= 1) {
        ps += __shfl_xor(ps, m);
        pd += __shfl_xor(pd, m);
    }
    if ((c & 31) == 0) {
        int hd = c >> 5;
        asrc[n * 4 + hd] = ps;
        adst[n * 4 + hd] = pd;
    }
}

// ---- layer1 gather-aggregate v2: edge-parallel softmax in LDS, heads=4 ----
__global__ __launch_bounds__(128) void k_agg1v(
        const int* __restrict__ off, const int* __restrict__ csr,
        const float* __restrict__ asrc, const float* __restrict__ adst,
        const float* __restrict__ h, float* __restrict__ ob) {
    __shared__ float2 pair[DCAP1 * 4];     // {ex, src_bits} per (edge, head)
    __shared__ float redm[4], redd[4];
    int n = blockIdx.x, t = threadIdx.x;
    int hd = t >> 5, l = t & 31;
    int e0 = off[n], deg = off[n + 1] - e0;
    float ad = adst[n * 4 + hd];

    if (deg <= DCAP1) {
        // phase A: per-edge alpha (parallel over edges within each head group)
        float mymax = -1e30f;
        for (int e = l; e < deg; e += 32) {
            int s = csr[e0 + e];
            float al = lrelu(asrc[s * 4 + hd] + ad);
            pair[e * 4 + hd] = make_float2(al, __int_as_float(s));
            mymax = fmaxf(mymax, al);
        }
#pragma unroll
        for (int m = 16; m >= 1; m >>= 1) mymax = fmaxf(mymax, __shfl_xor(mymax, m));
        if (l == 0) redm[hd] = mymax;
        __syncthreads();
        float amax = redm[hd];
        // phase A2: exp in place + denom
        float myden = 0.f;
        for (int e = l; e < deg; e += 32) {
            float ex = __expf(pair[e * 4 + hd].x - amax);
            pair[e * 4 + hd].x = ex;
            myden += ex;
        }
#pragma unroll
        for (int m = 16; m >= 1; m >>= 1) myden += __shfl_xor(myden, m);
        if (l == 0) redd[hd] = myden;
        __syncthreads();
        float inv = 1.f / (redd[hd] + 1e-16f);
        // phase B: gather-FMA, channel-parallel
        const float* hc = h + t;
        float acc = 0.f;
#pragma unroll 4
        for (int e = 0; e < deg; ++e) {
            float2 p = pair[e * 4 + hd];
            acc = fmaf(p.x, hc[(size_t)__float_as_int(p.y) * 128], acc);
        }
        ob[(size_t)n * 128 + t] = acc * inv;
    } else {
        // fallback (degree overflow; block-uniform branch)
        float amax = -1e30f;
        for (int e = e0; e < e0 + deg; ++e) {
            int s = csr[e];
            amax = fmaxf(amax, lrelu(asrc[s * 4 + hd] + ad));
        }
        float den = 0.f, acc = 0.f;
        for (int e = e0; e < e0 + deg; ++e) {
            int s = csr[e];
            float ex = __expf(lrelu(asrc[s * 4 + hd] + ad) - amax);
            den += ex;
            acc = fmaf(ex, h[(size_t)s * 128 + t], acc);
        }
        ob[(size_t)n * 128 + t] = acc / (den + 1e-16f);
    }
}

// ---- layer2 node transform, register-tiled GEMM:
//      x2 = relu(out1+b1); h2 = x2@W2 ; fused attention dots ----
__global__ __launch_bounds__(256) void k_node2t(
        const float* __restrict__ ob, const float* __restrict__ b1,
        const float* __restrict__ W2, const float* __restrict__ as2,
        const float* __restrict__ ad2, float* __restrict__ h2,
        float* __restrict__ asrc, float* __restrict__ adst) {
    __shared__ float Wl[32][128];   // one 32-row K-chunk of W2
    __shared__ float xt[32][128];   // 32 rows of relu(out1+b1)
    int t = threadIdx.x;
    int tc = t & 31, tr = t >> 5;         // col group 0..31, row group 0..7
    int n0 = blockIdx.x * 32;

#pragma unroll
    for (int i = 0; i < 4; ++i) {
        int f4 = t + i * 256;             // 0..1023
        int r = f4 >> 5, c4 = f4 & 31;
        float4 v = make_float4(0.f, 0.f, 0.f, 0.f);
        int n = n0 + r;
        if (n < NN) {
            v = *(const float4*)(ob + (size_t)n * 128 + c4 * 4);
            float4 bb = *(const float4*)(b1 + c4 * 4);
            v.x = fmaxf(v.x + bb.x, 0.f);
            v.y = fmaxf(v.y + bb.y, 0.f);
            v.z = fmaxf(v.z + bb.z, 0.f);
            v.w = fmaxf(v.w + bb.w, 0.f);
        }
        *(float4*)(&xt[r][c4 * 4]) = v;
    }

    float acc[4][4] = {{0.f}};
#pragma unroll
    for (int kc = 0; kc < 4; ++kc) {
        __syncthreads();
#pragma unroll
        for (int i = 0; i < 4; ++i) {
            int f4 = t + i * 256;
            int r = f4 >> 5, c4 = f4 & 31;
            *(float4*)(&Wl[r][c4 * 4]) =
                *(const float4*)(W2 + (size_t)(kc * 32 + r) * 128 + c4 * 4);
        }
        __syncthreads();
#pragma unroll
        for (int k = 0; k < 32; ++k) {
            float4 w = *(const float4*)(&Wl[k][tc * 4]);
            float x0 = xt[tr * 4 + 0][kc * 32 + k];
            float x1 = xt[tr * 4 + 1][kc * 32 + k];
            float x2 = xt[tr * 4 + 2][kc * 32 + k];
            float x3 = xt[tr * 4 + 3][kc * 32 + k];
            acc[0][0] = fmaf(x0, w.x, acc[0][0]);
            acc[0][1] = fmaf(x0, w.y, acc[0][1]);
            acc[0][2] = fmaf(x0, w.z, acc[0][2]);
            acc[0][3] = fmaf(x0, w.w, acc[0][3]);
            acc[1][0] = fmaf(x1, w.x, acc[1][0]);
            acc[1][1] = fmaf(x1, w.y, acc[1][1]);
            acc[1][2] = fmaf(x1, w.z, acc[1][2]);
            acc[1][3] = fmaf(x1, w.w, acc[1][3]);
            acc[2][0] = fmaf(x2, w.x, acc[2][0]);
            acc[2][1] = fmaf(x2, w.y, acc[2][1]);
            acc[2][2] = fmaf(x2, w.z, acc[2][2]);
            acc[2][3] = fmaf(x2, w.w, acc[2][3]);
            acc[3][0] = fmaf(x3, w.x, acc[3][0]);
            acc[3][1] = fmaf(x3, w.y, acc[3][1]);
            acc[3][2] = fmaf(x3, w.z, acc[3][2]);
            acc[3][3] = fmaf(x3, w.w, acc[3][3]);
        }
    }

    float4 av = *(const float4*)(as2 + tc * 4);
    float4 dv = *(const float4*)(ad2 + tc * 4);
#pragma unroll
    for (int j = 0; j < 4; ++j) {
        int n = n0 + tr * 4 + j;
        float ps = acc[j][0] * av.x + acc[j][1] * av.y +
                   acc[j][2] * av.z + acc[j][3] * av.w;
        float pd = acc[j][0] * dv.x + acc[j][1] * dv.y +
                   acc[j][2] * dv.z + acc[j][3] * dv.w;
#pragma unroll
        for (int m = 16; m >= 1; m >>= 1) {
            ps += __shfl_xor(ps, m);
            pd += __shfl_xor(pd, m);
        }
        if (n < NN) {
            *(float4*)(h2 + (size_t)n * 128 + tc * 4) =
                make_float4(acc[j][0], acc[j][1], acc[j][2], acc[j][3]);
            if (tc == 0) { asrc[n] = ps; adst[n] = pd; }
        }
    }
}

// ---- layer2 gather-aggregate v2: edge-parallel softmax in LDS, heads=1 ----
__global__ __launch_bounds__(128) void k_agg2v(
        const int* __restrict__ off, const int* __restrict__ csr,
        const float* __restrict__ asrc, const float* __restrict__ adst,
        const float* __restrict__ h, float* __restrict__ ob) {
    __shared__ float2 pair[DCAP2];         // {ex, src_bits} per edge
    __shared__ float red[4];
    int n = blockIdx.x, t = threadIdx.x;
    int e0 = off[n], deg = off[n + 1] - e0;
    float ad = adst[n];

    if (deg <= DCAP2) {
        float mymax = -1e30f;
        for (int e = t; e < deg; e += 128) {
            int s = csr[e0 + e];
            float al = lrelu(asrc[s] + ad);
            pair[e] = make_float2(al, __int_as_float(s));
            mymax = fmaxf(mymax, al);
        }
#pragma unroll
        for (int m = 32; m >= 1; m >>= 1) mymax = fmaxf(mymax, __shfl_xor(mymax, m));
        if ((t & 63) == 0) red[t >> 6] = mymax;
        __syncthreads();
        float amax = fmaxf(red[0], red[1]);
        float myden = 0.f;
        for (int e = t; e < deg; e += 128) {
            float ex = __expf(pair[e].x - amax);
            pair[e].x = ex;
            myden += ex;
        }
#pragma unroll
        for (int m = 32; m >= 1; m >>= 1) myden += __shfl_xor(myden, m);
        if ((t & 63) == 0) red[2 + (t >> 6)] = myden;
        __syncthreads();
        float inv = 1.f / (red[2] + red[3] + 1e-16f);
        const float* hc = h + t;
        float acc = 0.f;
#pragma unroll 4
        for (int e = 0; e < deg; ++e) {
            float2 p = pair[e];
            acc = fmaf(p.x, hc[(size_t)__float_as_int(p.y) * 128], acc);
        }
        ob[(size_t)n * 128 + t] = acc * inv;
    } else {
        float amax = -1e30f;
        for (int e = e0; e < e0 + deg; ++e) {
            int s = csr[e];
            amax = fmaxf(amax, lrelu(asrc[s] + ad));
        }
        float den = 0.f, acc = 0.f;
        for (int e = e0; e < e0 + deg; ++e) {
            int s = csr[e];
            float ex = __expf(lrelu(asrc[s] + ad) - amax);
            den += ex;
            acc = fmaf(ex, h[(size_t)s * 128 + t], acc);
        }
        ob[(size_t)n * 128 + t] = acc / (den + 1e-16f);
    }
}

// ---- final: mean over nodes, d_out pre-set to b2 ----
__global__ __launch_bounds__(128) void k_final(const float* __restrict__ ob,
                                               float* __restrict__ out) {
    int c = threadIdx.x;
    float acc = 0.f;
    for (int n = blockIdx.x; n < NN; n += gridDim.x) acc += ob[n * 128 + c];
    atomicAdd(out + c, acc * (1.0f / NN));
}

extern "C" void kernel_launch(void* const* d_in, const int* in_sizes, int n_in,
                              void* d_out, int out_size, void* d_ws, size_t ws_size,
                              hipStream_t stream) {
    const float* x   = (const float*)d_in[0];
    const int*   ei  = (const int*)d_in[1];
    const float* W1  = (const float*)d_in[2];
    const float* as1 = (const float*)d_in[3];
    const float* ad1 = (const float*)d_in[4];
    const float* b1  = (const float*)d_in[5];
    const float* W2  = (const float*)d_in[6];
    const float* as2 = (const float*)d_in[7];
    const float* ad2 = (const float*)d_in[8];
    const float* b2  = (const float*)d_in[9];
    float* out = (float*)d_out;

    float* ws   = (float*)d_ws;
    float* h    = ws;                    // NN*128 (h1 then h2)
    float* ob   = h + NN * 128;          // NN*128 (out1 then out2)
    float* asr1 = ob + NN * 128;         // NN*4
    float* adt1 = asr1 + NN * 4;         // NN*4
    float* asr2 = adt1 + NN * 4;         // NN
    float* adt2 = asr2 + NN;             // NN
    int* deg    = (int*)(adt2 + NN);     // NN
    int* off    = deg + NN;              // NN+1
    int* cur    = off + NN + 1;          // NN
    int* bsum   = cur + NN;              // NBLK
    int* csr    = bsum + NBLK;           // ET

    // CSR build (shared by both layers)
    k_init<<<(NN + 255) / 256, 256, 0, stream>>>(deg, b2, out);
    k_deg<<<(ET + 255) / 256, 256, 0, stream>>>(ei, deg);
    k_scan_a<<<NBLK, SCAN_B, 0, stream>>>(deg, off, bsum);
    k_scan_b<<<1, SCAN_B, 0, stream>>>(bsum, off);
    k_scan_c<<<NBLK, SCAN_B, 0, stream>>>(off, bsum, cur);
    k_fill<<<(ET + 255) / 256, 256, 0, stream>>>(ei, cur, csr);

    // layer 1
    k_node1<<<NN, 128, 0, stream>>>(x, W1, as1, ad1, h, asr1, adt1);
    k_agg1v<<<NN, 128, 0, stream>>>(off, csr, asr1, adt1, h, ob);

    // layer 2 (h reused for h2, ob overwritten by out2)
    k_node2t<<<(NN + 31) / 32, 256, 0, stream>>>(ob, b1, W2, as2, ad2, h, asr2, adt2);
    k_agg2v<<<NN, 128, 0, stream>>>(off, csr, asr2, adt2, h, ob);

    // mean pool (+b2 already in out)
    k_final<<<256, 128, 0, stream>>>(ob, out);
}